// Round 16
// baseline (134.414 us; speedup 1.0000x reference)
//
#include <hip/hip_runtime.h>
#include <hip/hip_fp16.h>

// GCN policy net: 2× GCNConv(H=16) + global max pool + linear head.
// Build: fixed-capacity coarse buckets -> k_bin (TILE=2048 x 512 thr, wave-
// shfl scan: 2 barriers instead of 18) -> k_sort (1024 thr, uint4-vectorized
// single pairs read, wave-shfl scan; 4-aligned segments, sentinel pad ->
// zero g16 row; off2 + dis).
// Compute: MFMA f16 gemm1; layer-1 agg fuses the 16x16 W2 matmul in its
// epilogue -> g16b; layer-2 agg fuses global max pool. Separate k_final
// (round-12 lesson: per-block __threadfence = full-L2 writeback x blocks).

#define FIN 128
#define HDIM 16
#define AOUT 10
#define NPB 256      // nodes per bucket (bucket = dst >> 8)
#define KMAX 512     // LDS sizing bound (padded): supports n <= 131072
#define TILE 2048    // edges per k_bin tile
#define CAP 10240    // bucket capacity (max count ~8560 + align pad <=768)

typedef _Float16 f16x8 __attribute__((ext_vector_type(8)));
typedef float f32x4 __attribute__((ext_vector_type(4)));

// init bucket cursors; zero pooled; zero sentinel rows of g16 buffers
__global__ void k_init(int* __restrict__ bcur, unsigned int* __restrict__ pooled,
                       unsigned int* __restrict__ gza, unsigned int* __restrict__ gzb,
                       int K) {
    int i = blockIdx.x * 256 + threadIdx.x;
    if (i < K) bcur[i] = i * CAP;
    if (i < 16) pooled[i] = 0u;
    if (i < 8) { gza[i] = 0u; gzb[i] = 0u; }   // 32B zero rows
}

// tile-local reorder: histogram -> wave-shfl scan (2 barriers) ->
// bucket-sorted LDS buffer -> linear coalesced copy-out.
__global__ __launch_bounds__(512) void k_bin(const int* __restrict__ src,
                                             const int* __restrict__ dst, int E,
                                             int* __restrict__ bcur,
                                             unsigned int* __restrict__ pairs, int K) {
    __shared__ int hist[KMAX], lofs[KMAX], run[KMAX], gbase[KMAX];
    __shared__ int wsum[8];
    __shared__ unsigned int buf[TILE];
    __shared__ unsigned short bkt[TILE];
    int t = threadIdx.x;
    int lane = t & 63, wv = t >> 6;
    int e0 = blockIdx.x * TILE;
    int e1 = min(E, e0 + TILE);
    hist[t] = 0;                       // blockDim == KMAX == 512
    __syncthreads();
    // phase 1: tile histogram (1 int4 per thread)
    int e = e0 + t * 4;
    if (e + 4 <= e1) {
        int4 d4 = *reinterpret_cast<const int4*>(dst + e);
        atomicAdd(&hist[d4.x >> 8], 1);
        atomicAdd(&hist[d4.y >> 8], 1);
        atomicAdd(&hist[d4.z >> 8], 1);
        atomicAdd(&hist[d4.w >> 8], 1);
    } else {
        for (int q = e; q < e1; q++) atomicAdd(&hist[dst[q] >> 8], 1);
    }
    __syncthreads();
    // phase 2: exclusive scan via wave shfl (2 barriers total)
    int a = hist[t];
    int v = a;
#pragma unroll
    for (int d = 1; d < 64; d <<= 1) {
        int u = __shfl_up(v, d);
        if (lane >= d) v += u;
    }
    if (lane == 63) wsum[wv] = v;
    __syncthreads();
    int woff = 0;
#pragma unroll
    for (int w2 = 0; w2 < 8; w2++) woff += (w2 < wv) ? wsum[w2] : 0;
    int excl = v + woff - a;           // exclusive prefix
    lofs[t] = excl;
    run[t] = excl;
    // reserve global windows (one atomic per non-empty bucket)
    if (t < K && a) gbase[t] = atomicAdd(&bcur[t], a);
    __syncthreads();
    // phase 3: scatter into bucket-sorted LDS buffer (1 int4 per thread)
    if (e + 4 <= e1) {
        int4 d4 = *reinterpret_cast<const int4*>(dst + e);
        int4 s4 = *reinterpret_cast<const int4*>(src + e);
        int b, r;
        b = d4.x >> 8; r = atomicAdd(&run[b], 1);
        buf[r] = (unsigned)s4.x | ((unsigned)(d4.x & 255) << 17); bkt[r] = (unsigned short)b;
        b = d4.y >> 8; r = atomicAdd(&run[b], 1);
        buf[r] = (unsigned)s4.y | ((unsigned)(d4.y & 255) << 17); bkt[r] = (unsigned short)b;
        b = d4.z >> 8; r = atomicAdd(&run[b], 1);
        buf[r] = (unsigned)s4.z | ((unsigned)(d4.z & 255) << 17); bkt[r] = (unsigned short)b;
        b = d4.w >> 8; r = atomicAdd(&run[b], 1);
        buf[r] = (unsigned)s4.w | ((unsigned)(d4.w & 255) << 17); bkt[r] = (unsigned short)b;
    } else {
        for (int q = e; q < e1; q++) {
            int d = dst[q], s = src[q], b = d >> 8;
            int r = atomicAdd(&run[b], 1);
            buf[r] = (unsigned)s | ((unsigned)(d & 255) << 17);
            bkt[r] = (unsigned short)b;
        }
    }
    __syncthreads();
    // phase 4: linear coalesced copy-out
    int m = e1 - e0;
    for (int i = t; i < m; i += 512) {
        int b = bkt[i];
        pairs[gbase[b] + i - lofs[b]] = buf[i];
    }
}

// per-bucket counting sort (1024 thr, uint4-vectorized single pairs read,
// wave-shfl scan) -> node-ordered srcidx with 4-aligned segments + off2 + dis.
__global__ __launch_bounds__(1024) void k_sort(const unsigned int* __restrict__ pairs,
                                               const int* __restrict__ bcur,
                                               int* __restrict__ srcidx,
                                               int2* __restrict__ off2,
                                               float* __restrict__ dis, int n) {
    __shared__ int lcnt[NPB], cur[NPB];
    __shared__ int wsum4[4];
    int b = blockIdx.x, t = threadIdx.x;
    int lane = t & 63, wv = t >> 6;
    if (t < NPB) lcnt[t] = 0;
    __syncthreads();
    int base = b * CAP;
    int m = bcur[b] - base;
    int m4 = (m + 3) >> 2;             // uint4 count
    const uint4* p4 = reinterpret_cast<const uint4*>(pairs + base);
    uint4 l0 = {0,0,0,0}, l1 = {0,0,0,0}, l2 = {0,0,0,0};
    if (t < m4) {
        l0 = p4[t];
        int jj = t * 4;
        atomicAdd(&lcnt[l0.x >> 17], 1);
        if (jj + 1 < m) atomicAdd(&lcnt[l0.y >> 17], 1);
        if (jj + 2 < m) atomicAdd(&lcnt[l0.z >> 17], 1);
        if (jj + 3 < m) atomicAdd(&lcnt[l0.w >> 17], 1);
    }
    if (t + 1024 < m4) {
        l1 = p4[t + 1024];
        int jj = (t + 1024) * 4;
        atomicAdd(&lcnt[l1.x >> 17], 1);
        if (jj + 1 < m) atomicAdd(&lcnt[l1.y >> 17], 1);
        if (jj + 2 < m) atomicAdd(&lcnt[l1.z >> 17], 1);
        if (jj + 3 < m) atomicAdd(&lcnt[l1.w >> 17], 1);
    }
    if (t + 2048 < m4) {
        l2 = p4[t + 2048];
        int jj = (t + 2048) * 4;
        atomicAdd(&lcnt[l2.x >> 17], 1);
        if (jj + 1 < m) atomicAdd(&lcnt[l2.y >> 17], 1);
        if (jj + 2 < m) atomicAdd(&lcnt[l2.z >> 17], 1);
        if (jj + 3 < m) atomicAdd(&lcnt[l2.w >> 17], 1);
    }
    __syncthreads();
    // wave-shfl exclusive scan over aligned sizes (threads 0..255 = 4 waves)
    int v = (t < NPB) ? lcnt[t] : 0;
    int w = (v + 3) & ~3;              // 4-aligned segment size
    int s = w;
    if (t < NPB) {
#pragma unroll
        for (int d = 1; d < 64; d <<= 1) {
            int u = __shfl_up(s, d);
            if (lane >= d) s += u;
        }
        if (lane == 63) wsum4[wv] = s;
    }
    __syncthreads();
    if (t < NPB) {
        int woff = 0;
#pragma unroll
        for (int w2 = 0; w2 < 4; w2++) woff += (w2 < wv) ? wsum4[w2] : 0;
        int start = s + woff - w;      // exclusive prefix
        cur[t] = start;
        int node = (b << 8) + t;
        if (node < n) {
            off2[node] = make_int2(base + start, base + start + v);
            dis[node] = rsqrtf((float)(v + 1));
        }
        for (int p = v; p < w; p++) srcidx[base + start + p] = n;  // sentinel
    }
    __syncthreads();
    // scatter from registers
    if (t < m4) {
        int jj = t * 4;
        unsigned p;
        p = l0.x; srcidx[base + atomicAdd(&cur[p >> 17], 1)] = (int)(p & 0x1FFFF);
        if (jj + 1 < m) { p = l0.y; srcidx[base + atomicAdd(&cur[p >> 17], 1)] = (int)(p & 0x1FFFF); }
        if (jj + 2 < m) { p = l0.z; srcidx[base + atomicAdd(&cur[p >> 17], 1)] = (int)(p & 0x1FFFF); }
        if (jj + 3 < m) { p = l0.w; srcidx[base + atomicAdd(&cur[p >> 17], 1)] = (int)(p & 0x1FFFF); }
    }
    if (t + 1024 < m4) {
        int jj = (t + 1024) * 4;
        unsigned p;
        p = l1.x; srcidx[base + atomicAdd(&cur[p >> 17], 1)] = (int)(p & 0x1FFFF);
        if (jj + 1 < m) { p = l1.y; srcidx[base + atomicAdd(&cur[p >> 17], 1)] = (int)(p & 0x1FFFF); }
        if (jj + 2 < m) { p = l1.z; srcidx[base + atomicAdd(&cur[p >> 17], 1)] = (int)(p & 0x1FFFF); }
        if (jj + 3 < m) { p = l1.w; srcidx[base + atomicAdd(&cur[p >> 17], 1)] = (int)(p & 0x1FFFF); }
    }
    if (t + 2048 < m4) {
        int jj = (t + 2048) * 4;
        unsigned p;
        p = l2.x; srcidx[base + atomicAdd(&cur[p >> 17], 1)] = (int)(p & 0x1FFFF);
        if (jj + 1 < m) { p = l2.y; srcidx[base + atomicAdd(&cur[p >> 17], 1)] = (int)(p & 0x1FFFF); }
        if (jj + 2 < m) { p = l2.z; srcidx[base + atomicAdd(&cur[p >> 17], 1)] = (int)(p & 0x1FFFF); }
        if (jj + 3 < m) { p = l2.w; srcidx[base + atomicAdd(&cur[p >> 17], 1)] = (int)(p & 0x1FFFF); }
    }
}

// MFMA gemm1: g16[nd][c] = f16(dis[nd] * (x @ W1)[nd][c]).
__global__ __launch_bounds__(256) void k_gemm1(const float* __restrict__ x,
                                               const float* __restrict__ W1,
                                               const float* __restrict__ dis,
                                               __half* __restrict__ g16, int n) {
    int l = threadIdx.x & 63;
    int cc = l & 15, kg = l >> 4;
    f16x8 bfrag[4];
#pragma unroll
    for (int kc = 0; kc < 4; kc++)
#pragma unroll
        for (int j = 0; j < 8; j++)
            bfrag[kc][j] = (_Float16)W1[(kc * 32 + kg * 8 + j) * HDIM + cc];
    int tile = blockIdx.x * 4 + (threadIdx.x >> 6);
    int node0 = tile * 16;
    if (node0 >= n) return;
    const float* xr = x + (size_t)(node0 + cc) * FIN;
    f32x4 acc = {0.f, 0.f, 0.f, 0.f};
#pragma unroll
    for (int kc = 0; kc < 4; kc++) {
        float4 xa = *reinterpret_cast<const float4*>(xr + kc * 32 + kg * 8);
        float4 xb = *reinterpret_cast<const float4*>(xr + kc * 32 + kg * 8 + 4);
        f16x8 a;
        a[0] = (_Float16)xa.x; a[1] = (_Float16)xa.y;
        a[2] = (_Float16)xa.z; a[3] = (_Float16)xa.w;
        a[4] = (_Float16)xb.x; a[5] = (_Float16)xb.y;
        a[6] = (_Float16)xb.z; a[7] = (_Float16)xb.w;
        acc = __builtin_amdgcn_mfma_f32_16x16x32_f16(a, bfrag[kc], acc, 0, 0, 0);
    }
#pragma unroll
    for (int i = 0; i < 4; i++) {
        int nd = node0 + kg * 4 + i;
        g16[(size_t)nd * HDIM + cc] = (__half)(dis[nd] * acc[i]);
    }
}

#define ACC4(V) \
    a0 = __hadd2(a0, __builtin_bit_cast(__half2, (V).x)); \
    a1 = __hadd2(a1, __builtin_bit_cast(__half2, (V).y)); \
    a2 = __hadd2(a2, __builtin_bit_cast(__half2, (V).z)); \
    a3 = __hadd2(a3, __builtin_bit_cast(__half2, (V).w));

#define GATHER_LOOP \
    int e = e0 + 4 * half; \
    for (; e + 8 < e1; e += 16) { \
        int4 sa = *reinterpret_cast<const int4*>(srcidx + e); \
        int4 sb = *reinterpret_cast<const int4*>(srcidx + e + 8); \
        uint4 w0 = gp[(size_t)sa.x * 2 + piece]; \
        uint4 w1 = gp[(size_t)sa.y * 2 + piece]; \
        uint4 w2 = gp[(size_t)sa.z * 2 + piece]; \
        uint4 w3 = gp[(size_t)sa.w * 2 + piece]; \
        uint4 w4 = gp[(size_t)sb.x * 2 + piece]; \
        uint4 w5 = gp[(size_t)sb.y * 2 + piece]; \
        uint4 w6 = gp[(size_t)sb.z * 2 + piece]; \
        uint4 w7 = gp[(size_t)sb.w * 2 + piece]; \
        ACC4(w0) ACC4(w1) ACC4(w2) ACC4(w3) \
        ACC4(w4) ACC4(w5) ACC4(w6) ACC4(w7) \
    } \
    for (; e < e1; e += 8) { \
        int4 sa = *reinterpret_cast<const int4*>(srcidx + e); \
        uint4 w0 = gp[(size_t)sa.x * 2 + piece]; \
        uint4 w1 = gp[(size_t)sa.y * 2 + piece]; \
        uint4 w2 = gp[(size_t)sa.z * 2 + piece]; \
        uint4 w3 = gp[(size_t)sa.w * 2 + piece]; \
        ACC4(w0) ACC4(w1) ACC4(w2) ACC4(w3) \
    } \
    a0 = __hadd2(a0, __builtin_bit_cast(__half2, __shfl_xor(__builtin_bit_cast(unsigned, a0), 2))); \
    a1 = __hadd2(a1, __builtin_bit_cast(__half2, __shfl_xor(__builtin_bit_cast(unsigned, a1), 2))); \
    a2 = __hadd2(a2, __builtin_bit_cast(__half2, __shfl_xor(__builtin_bit_cast(unsigned, a2), 2))); \
    a3 = __hadd2(a3, __builtin_bit_cast(__half2, __shfl_xor(__builtin_bit_cast(unsigned, a3), 2)));

// layer-1 aggregation + fused W2 matmul (quadrant split across 4 sub-lanes).
__global__ __launch_bounds__(256) void k_agg_g2(const __half* __restrict__ g16in,
                                                const int2* __restrict__ off2,
                                                const int* __restrict__ srcidx,
                                                const float* __restrict__ dis,
                                                const float* __restrict__ bias,
                                                const float* __restrict__ W2,
                                                __half* __restrict__ g16out, int n) {
    __shared__ float W2s[HDIM * HDIM];
    int t = threadIdx.x;
    W2s[t] = W2[t];     // blockDim == 256 == HDIM*HDIM
    __syncthreads();
    int tid = blockIdx.x * 256 + t;
    int node = tid >> 2, sub = t & 3;
    int piece = sub & 1, half = sub >> 1;
    if (node >= n) return;
    const uint4* gp = reinterpret_cast<const uint4*>(g16in);
    int2 oe = off2[node];
    int e0 = oe.x, e1 = oe.y;
    __half2 a0{0, 0}, a1{0, 0}, a2{0, 0}, a3{0, 0};
    if (half == 0) {  // self-loop term once
        uint4 v = gp[(size_t)node * 2 + piece];
        ACC4(v)
    }
    GATHER_LOOP
    // all lanes: relu'd h for channels piece*8 .. piece*8+7
    float dn = dis[node];
    const float* bp = bias + piece * 8;
    float2 f0 = __half22float2(a0), f1 = __half22float2(a1);
    float2 f2 = __half22float2(a2), f3 = __half22float2(a3);
    float hreg[8];
    hreg[0] = fmaxf(dn * f0.x + bp[0], 0.f); hreg[1] = fmaxf(dn * f0.y + bp[1], 0.f);
    hreg[2] = fmaxf(dn * f1.x + bp[2], 0.f); hreg[3] = fmaxf(dn * f1.y + bp[3], 0.f);
    hreg[4] = fmaxf(dn * f2.x + bp[4], 0.f); hreg[5] = fmaxf(dn * f2.y + bp[5], 0.f);
    hreg[6] = fmaxf(dn * f3.x + bp[6], 0.f); hreg[7] = fmaxf(dn * f3.y + bp[7], 0.f);
    // quadrant of h @ W2: j-range = piece*8.., c-range = half*8..
    float acc[8];
    const float* wq = W2s + (piece * 8) * HDIM + half * 8;
#pragma unroll
    for (int cc = 0; cc < 8; cc++) {
        float s = 0.f;
#pragma unroll
        for (int jj = 0; jj < 8; jj++) s += hreg[jj] * wq[jj * HDIM + cc];
        acc[cc] = s;
    }
    // combine j-halves across piece (bit 0)
#pragma unroll
    for (int cc = 0; cc < 8; cc++) acc[cc] += __shfl_xor(acc[cc], 1);
    if (piece == 0) {   // sub0 writes c 0-7, sub2 writes c 8-15
        __half o[8];
#pragma unroll
        for (int cc = 0; cc < 8; cc++) o[cc] = (__half)(dn * acc[cc]);
        *reinterpret_cast<uint4*>(g16out + (size_t)node * HDIM + half * 8) =
            *reinterpret_cast<uint4*>(o);
    }
}

// layer-2 aggregation + fused global max pool (h never written).
__global__ __launch_bounds__(256) void k_agg_pool(const __half* __restrict__ g16in,
                                                  const int2* __restrict__ off2,
                                                  const int* __restrict__ srcidx,
                                                  const float* __restrict__ dis,
                                                  const float* __restrict__ bias,
                                                  unsigned int* __restrict__ pooled,
                                                  int n) {
    __shared__ float smax[4][16];
    int t = threadIdx.x;
    int tid = blockIdx.x * 256 + t;
    int node = tid >> 2, sub = t & 3;
    int piece = sub & 1, half = sub >> 1;
    bool active = node < n;
    float4 o0 = {0.f, 0.f, 0.f, 0.f}, o1 = {0.f, 0.f, 0.f, 0.f};
    if (active) {
        const uint4* gp = reinterpret_cast<const uint4*>(g16in);
        int2 oe = off2[node];
        int e0 = oe.x, e1 = oe.y;
        __half2 a0{0, 0}, a1{0, 0}, a2{0, 0}, a3{0, 0};
        if (half == 0) {  // self-loop term once
            uint4 v = gp[(size_t)node * 2 + piece];
            ACC4(v)
        }
        GATHER_LOOP
        if (half == 0) {
            float dn = dis[node];
            const float* bp = bias + piece * 8;
            float2 f0 = __half22float2(a0), f1 = __half22float2(a1);
            float2 f2 = __half22float2(a2), f3 = __half22float2(a3);
            o0.x = fmaxf(dn * f0.x + bp[0], 0.f); o0.y = fmaxf(dn * f0.y + bp[1], 0.f);
            o0.z = fmaxf(dn * f1.x + bp[2], 0.f); o0.w = fmaxf(dn * f1.y + bp[3], 0.f);
            o1.x = fmaxf(dn * f2.x + bp[4], 0.f); o1.y = fmaxf(dn * f2.y + bp[5], 0.f);
            o1.z = fmaxf(dn * f3.x + bp[6], 0.f); o1.w = fmaxf(dn * f3.y + bp[7], 0.f);
        }
    }
    // wave-reduce over nodes (xor >= 4 preserves sub class); h >= 0
#pragma unroll
    for (int d = 4; d <= 32; d <<= 1) {
        o0.x = fmaxf(o0.x, __shfl_xor(o0.x, d)); o0.y = fmaxf(o0.y, __shfl_xor(o0.y, d));
        o0.z = fmaxf(o0.z, __shfl_xor(o0.z, d)); o0.w = fmaxf(o0.w, __shfl_xor(o0.w, d));
        o1.x = fmaxf(o1.x, __shfl_xor(o1.x, d)); o1.y = fmaxf(o1.y, __shfl_xor(o1.y, d));
        o1.z = fmaxf(o1.z, __shfl_xor(o1.z, d)); o1.w = fmaxf(o1.w, __shfl_xor(o1.w, d));
    }
    int wv = t >> 6;
    if ((t & 63) < 2) {  // lane 0: piece0, lane 1: piece1 (half==0 class)
        float* sp = &smax[wv][piece * 8];
        sp[0] = o0.x; sp[1] = o0.y; sp[2] = o0.z; sp[3] = o0.w;
        sp[4] = o1.x; sp[5] = o1.y; sp[6] = o1.z; sp[7] = o1.w;
    }
    __syncthreads();
    if (t < 16) {
        float m = fmaxf(fmaxf(smax[0][t], smax[1][t]), fmaxf(smax[2][t], smax[3][t]));
        atomicMax(&pooled[t], __float_as_uint(m));
    }
}

// out[a] = sum_c pooled[c] * Wc[c][a] + bc[a]   (Wc: [16,10])
__global__ void k_final(const unsigned int* __restrict__ pooled, const float* __restrict__ Wc,
                        const float* __restrict__ bc, float* __restrict__ out) {
    __shared__ float p[HDIM];
    int t = threadIdx.x;
    if (t < HDIM) p[t] = __uint_as_float(pooled[t]);
    __syncthreads();
    if (t < AOUT) {
        float acc = bc[t];
#pragma unroll
        for (int c = 0; c < HDIM; c++) acc += p[c] * Wc[c * AOUT + t];
        out[t] = acc;
    }
}

extern "C" void kernel_launch(void* const* d_in, const int* in_sizes, int n_in,
                              void* d_out, int out_size, void* d_ws, size_t ws_size,
                              hipStream_t stream) {
    const float* x  = (const float*)d_in[0];
    const int*   ei = (const int*)d_in[1];
    const float* W1 = (const float*)d_in[2];
    const float* b1 = (const float*)d_in[3];
    const float* W2 = (const float*)d_in[4];
    const float* b2 = (const float*)d_in[5];
    const float* Wc = (const float*)d_in[6];
    const float* bc = (const float*)d_in[7];
    float* out = (float*)d_out;

    int n = in_sizes[0] / FIN;
    int E = in_sizes[1] / 2;
    const int* srcp = ei;       // edge_index[0]
    const int* dstp = ei + E;   // edge_index[1]
    int K = (n + NPB - 1) / NPB;   // 391 for n=100000

    char* ws = (char*)d_ws;
    auto alloc = [&](size_t bytes) -> char* {
        char* p = ws;
        ws += (bytes + 255) & ~(size_t)255;
        return p;
    };
    float*        dis   = (float*)alloc((size_t)n * 4);
    int*          bcur  = (int*)alloc((size_t)K * 4);
    int2*         off2  = (int2*)alloc((size_t)n * 8);
    unsigned int* pairs = (unsigned int*)alloc((size_t)K * CAP * 4);
    int*          srcidx= (int*)alloc((size_t)K * CAP * 4);
    __half*       g16a  = (__half*)alloc((size_t)(n + 1) * HDIM * 2);
    __half*       g16b  = (__half*)alloc((size_t)(n + 1) * HDIM * 2);
    unsigned int* pooled= (unsigned int*)alloc(64);

    k_init<<<(K + 255) / 256, 256, 0, stream>>>(
        bcur, pooled,
        (unsigned int*)(g16a + (size_t)n * HDIM),
        (unsigned int*)(g16b + (size_t)n * HDIM), K);
    k_bin<<<(E + TILE - 1) / TILE, 512, 0, stream>>>(srcp, dstp, E, bcur, pairs, K);
    k_sort<<<K, 1024, 0, stream>>>(pairs, bcur, srcidx, off2, dis, n);

    int ntile = (n + 15) / 16;
    int gblocks = (ntile + 3) / 4;
    k_gemm1<<<gblocks, 256, 0, stream>>>(x, W1, dis, g16a, n);
    k_agg_g2<<<(4 * n + 255) / 256, 256, 0, stream>>>(g16a, off2, srcidx, dis, b1,
                                                      W2, g16b, n);
    k_agg_pool<<<(4 * n + 255) / 256, 256, 0, stream>>>(g16b, off2, srcidx, dis, b2,
                                                        pooled, n);

    k_final<<<1, 64, 0, stream>>>(pooled, Wc, bc, out);
}

// Round 17
// 123.519 us; speedup vs baseline: 1.0882x; 1.0882x over previous
//
#include <hip/hip_runtime.h>
#include <hip/hip_fp16.h>

// GCN policy net: 2× GCNConv(H=16) + global max pool + linear head.
// Build: fixed-capacity coarse buckets -> k_bin (TILE=4096 x 512 thr —
// round-15 showed TILE=2048 regresses: k_bin is chain-throughput-bound,
// not occupancy-bound; wave-shfl scan: 2 barriers) -> k_sort (1024 thr,
// uint4-vectorized single pairs read, wave-shfl scan; 4-aligned segments,
// sentinel pad -> zero g16 row; off2 + dis).
// Compute: MFMA f16 gemm1; layer-1 agg fuses the 16x16 W2 matmul in its
// epilogue -> g16b; layer-2 agg fuses global max pool. Separate k_final
// (round-12 lesson: per-block __threadfence = full-L2 writeback x blocks).

#define FIN 128
#define HDIM 16
#define AOUT 10
#define NPB 256      // nodes per bucket (bucket = dst >> 8)
#define KMAX 512     // LDS sizing bound (padded): supports n <= 131072
#define TILE 4096    // edges per k_bin tile (2048 proven worse, round 15)
#define CAP 10240    // bucket capacity (max count ~8560 + align pad <=768)

typedef _Float16 f16x8 __attribute__((ext_vector_type(8)));
typedef float f32x4 __attribute__((ext_vector_type(4)));

// init bucket cursors; zero pooled; zero sentinel rows of g16 buffers
__global__ void k_init(int* __restrict__ bcur, unsigned int* __restrict__ pooled,
                       unsigned int* __restrict__ gza, unsigned int* __restrict__ gzb,
                       int K) {
    int i = blockIdx.x * 256 + threadIdx.x;
    if (i < K) bcur[i] = i * CAP;
    if (i < 16) pooled[i] = 0u;
    if (i < 8) { gza[i] = 0u; gzb[i] = 0u; }   // 32B zero rows
}

// tile-local reorder: histogram -> wave-shfl scan (2 barriers) ->
// bucket-sorted LDS buffer -> linear coalesced copy-out.
__global__ __launch_bounds__(512) void k_bin(const int* __restrict__ src,
                                             const int* __restrict__ dst, int E,
                                             int* __restrict__ bcur,
                                             unsigned int* __restrict__ pairs, int K) {
    __shared__ int hist[KMAX], lofs[KMAX], run[KMAX], gbase[KMAX];
    __shared__ int wsum[8];
    __shared__ unsigned int buf[TILE];
    __shared__ unsigned short bkt[TILE];
    int t = threadIdx.x;
    int lane = t & 63, wv = t >> 6;
    int e0 = blockIdx.x * TILE;
    int e1 = min(E, e0 + TILE);
    hist[t] = 0;                       // blockDim == KMAX == 512
    __syncthreads();
    // phase 1: tile histogram (2 int4 iterations per thread)
    for (int e = e0 + t * 4; e < e1; e += 2048) {
        if (e + 4 <= e1) {
            int4 d4 = *reinterpret_cast<const int4*>(dst + e);
            atomicAdd(&hist[d4.x >> 8], 1);
            atomicAdd(&hist[d4.y >> 8], 1);
            atomicAdd(&hist[d4.z >> 8], 1);
            atomicAdd(&hist[d4.w >> 8], 1);
        } else {
            for (int q = e; q < e1; q++) atomicAdd(&hist[dst[q] >> 8], 1);
        }
    }
    __syncthreads();
    // phase 2: exclusive scan via wave shfl (2 barriers total)
    int a = hist[t];
    int v = a;
#pragma unroll
    for (int d = 1; d < 64; d <<= 1) {
        int u = __shfl_up(v, d);
        if (lane >= d) v += u;
    }
    if (lane == 63) wsum[wv] = v;
    __syncthreads();
    int woff = 0;
#pragma unroll
    for (int w2 = 0; w2 < 8; w2++) woff += (w2 < wv) ? wsum[w2] : 0;
    int excl = v + woff - a;           // exclusive prefix
    lofs[t] = excl;
    run[t] = excl;
    // reserve global windows (one atomic per non-empty bucket)
    if (t < K && a) gbase[t] = atomicAdd(&bcur[t], a);
    __syncthreads();
    // phase 3: scatter into bucket-sorted LDS buffer
    for (int e = e0 + t * 4; e < e1; e += 2048) {
        if (e + 4 <= e1) {
            int4 d4 = *reinterpret_cast<const int4*>(dst + e);
            int4 s4 = *reinterpret_cast<const int4*>(src + e);
            int b, r;
            b = d4.x >> 8; r = atomicAdd(&run[b], 1);
            buf[r] = (unsigned)s4.x | ((unsigned)(d4.x & 255) << 17); bkt[r] = (unsigned short)b;
            b = d4.y >> 8; r = atomicAdd(&run[b], 1);
            buf[r] = (unsigned)s4.y | ((unsigned)(d4.y & 255) << 17); bkt[r] = (unsigned short)b;
            b = d4.z >> 8; r = atomicAdd(&run[b], 1);
            buf[r] = (unsigned)s4.z | ((unsigned)(d4.z & 255) << 17); bkt[r] = (unsigned short)b;
            b = d4.w >> 8; r = atomicAdd(&run[b], 1);
            buf[r] = (unsigned)s4.w | ((unsigned)(d4.w & 255) << 17); bkt[r] = (unsigned short)b;
        } else {
            for (int q = e; q < e1; q++) {
                int d = dst[q], s = src[q], b = d >> 8;
                int r = atomicAdd(&run[b], 1);
                buf[r] = (unsigned)s | ((unsigned)(d & 255) << 17);
                bkt[r] = (unsigned short)b;
            }
        }
    }
    __syncthreads();
    // phase 4: linear coalesced copy-out
    int m = e1 - e0;
    for (int i = t; i < m; i += 512) {
        int b = bkt[i];
        pairs[gbase[b] + i - lofs[b]] = buf[i];
    }
}

// per-bucket counting sort (1024 thr, uint4-vectorized single pairs read,
// wave-shfl scan) -> node-ordered srcidx with 4-aligned segments + off2 + dis.
__global__ __launch_bounds__(1024) void k_sort(const unsigned int* __restrict__ pairs,
                                               const int* __restrict__ bcur,
                                               int* __restrict__ srcidx,
                                               int2* __restrict__ off2,
                                               float* __restrict__ dis, int n) {
    __shared__ int lcnt[NPB], cur[NPB];
    __shared__ int wsum4[4];
    int b = blockIdx.x, t = threadIdx.x;
    int lane = t & 63, wv = t >> 6;
    if (t < NPB) lcnt[t] = 0;
    __syncthreads();
    int base = b * CAP;
    int m = bcur[b] - base;
    int m4 = (m + 3) >> 2;             // uint4 count
    const uint4* p4 = reinterpret_cast<const uint4*>(pairs + base);
    uint4 l0 = {0,0,0,0}, l1 = {0,0,0,0}, l2 = {0,0,0,0};
    if (t < m4) {
        l0 = p4[t];
        int jj = t * 4;
        atomicAdd(&lcnt[l0.x >> 17], 1);
        if (jj + 1 < m) atomicAdd(&lcnt[l0.y >> 17], 1);
        if (jj + 2 < m) atomicAdd(&lcnt[l0.z >> 17], 1);
        if (jj + 3 < m) atomicAdd(&lcnt[l0.w >> 17], 1);
    }
    if (t + 1024 < m4) {
        l1 = p4[t + 1024];
        int jj = (t + 1024) * 4;
        atomicAdd(&lcnt[l1.x >> 17], 1);
        if (jj + 1 < m) atomicAdd(&lcnt[l1.y >> 17], 1);
        if (jj + 2 < m) atomicAdd(&lcnt[l1.z >> 17], 1);
        if (jj + 3 < m) atomicAdd(&lcnt[l1.w >> 17], 1);
    }
    if (t + 2048 < m4) {
        l2 = p4[t + 2048];
        int jj = (t + 2048) * 4;
        atomicAdd(&lcnt[l2.x >> 17], 1);
        if (jj + 1 < m) atomicAdd(&lcnt[l2.y >> 17], 1);
        if (jj + 2 < m) atomicAdd(&lcnt[l2.z >> 17], 1);
        if (jj + 3 < m) atomicAdd(&lcnt[l2.w >> 17], 1);
    }
    __syncthreads();
    // wave-shfl exclusive scan over aligned sizes (threads 0..255 = 4 waves)
    int v = (t < NPB) ? lcnt[t] : 0;
    int w = (v + 3) & ~3;              // 4-aligned segment size
    int s = w;
    if (t < NPB) {
#pragma unroll
        for (int d = 1; d < 64; d <<= 1) {
            int u = __shfl_up(s, d);
            if (lane >= d) s += u;
        }
        if (lane == 63) wsum4[wv] = s;
    }
    __syncthreads();
    if (t < NPB) {
        int woff = 0;
#pragma unroll
        for (int w2 = 0; w2 < 4; w2++) woff += (w2 < wv) ? wsum4[w2] : 0;
        int start = s + woff - w;      // exclusive prefix
        cur[t] = start;
        int node = (b << 8) + t;
        if (node < n) {
            off2[node] = make_int2(base + start, base + start + v);
            dis[node] = rsqrtf((float)(v + 1));
        }
        for (int p = v; p < w; p++) srcidx[base + start + p] = n;  // sentinel
    }
    __syncthreads();
    // scatter from registers
    if (t < m4) {
        int jj = t * 4;
        unsigned p;
        p = l0.x; srcidx[base + atomicAdd(&cur[p >> 17], 1)] = (int)(p & 0x1FFFF);
        if (jj + 1 < m) { p = l0.y; srcidx[base + atomicAdd(&cur[p >> 17], 1)] = (int)(p & 0x1FFFF); }
        if (jj + 2 < m) { p = l0.z; srcidx[base + atomicAdd(&cur[p >> 17], 1)] = (int)(p & 0x1FFFF); }
        if (jj + 3 < m) { p = l0.w; srcidx[base + atomicAdd(&cur[p >> 17], 1)] = (int)(p & 0x1FFFF); }
    }
    if (t + 1024 < m4) {
        int jj = (t + 1024) * 4;
        unsigned p;
        p = l1.x; srcidx[base + atomicAdd(&cur[p >> 17], 1)] = (int)(p & 0x1FFFF);
        if (jj + 1 < m) { p = l1.y; srcidx[base + atomicAdd(&cur[p >> 17], 1)] = (int)(p & 0x1FFFF); }
        if (jj + 2 < m) { p = l1.z; srcidx[base + atomicAdd(&cur[p >> 17], 1)] = (int)(p & 0x1FFFF); }
        if (jj + 3 < m) { p = l1.w; srcidx[base + atomicAdd(&cur[p >> 17], 1)] = (int)(p & 0x1FFFF); }
    }
    if (t + 2048 < m4) {
        int jj = (t + 2048) * 4;
        unsigned p;
        p = l2.x; srcidx[base + atomicAdd(&cur[p >> 17], 1)] = (int)(p & 0x1FFFF);
        if (jj + 1 < m) { p = l2.y; srcidx[base + atomicAdd(&cur[p >> 17], 1)] = (int)(p & 0x1FFFF); }
        if (jj + 2 < m) { p = l2.z; srcidx[base + atomicAdd(&cur[p >> 17], 1)] = (int)(p & 0x1FFFF); }
        if (jj + 3 < m) { p = l2.w; srcidx[base + atomicAdd(&cur[p >> 17], 1)] = (int)(p & 0x1FFFF); }
    }
}

// MFMA gemm1: g16[nd][c] = f16(dis[nd] * (x @ W1)[nd][c]).
__global__ __launch_bounds__(256) void k_gemm1(const float* __restrict__ x,
                                               const float* __restrict__ W1,
                                               const float* __restrict__ dis,
                                               __half* __restrict__ g16, int n) {
    int l = threadIdx.x & 63;
    int cc = l & 15, kg = l >> 4;
    f16x8 bfrag[4];
#pragma unroll
    for (int kc = 0; kc < 4; kc++)
#pragma unroll
        for (int j = 0; j < 8; j++)
            bfrag[kc][j] = (_Float16)W1[(kc * 32 + kg * 8 + j) * HDIM + cc];
    int tile = blockIdx.x * 4 + (threadIdx.x >> 6);
    int node0 = tile * 16;
    if (node0 >= n) return;
    const float* xr = x + (size_t)(node0 + cc) * FIN;
    f32x4 acc = {0.f, 0.f, 0.f, 0.f};
#pragma unroll
    for (int kc = 0; kc < 4; kc++) {
        float4 xa = *reinterpret_cast<const float4*>(xr + kc * 32 + kg * 8);
        float4 xb = *reinterpret_cast<const float4*>(xr + kc * 32 + kg * 8 + 4);
        f16x8 a;
        a[0] = (_Float16)xa.x; a[1] = (_Float16)xa.y;
        a[2] = (_Float16)xa.z; a[3] = (_Float16)xa.w;
        a[4] = (_Float16)xb.x; a[5] = (_Float16)xb.y;
        a[6] = (_Float16)xb.z; a[7] = (_Float16)xb.w;
        acc = __builtin_amdgcn_mfma_f32_16x16x32_f16(a, bfrag[kc], acc, 0, 0, 0);
    }
#pragma unroll
    for (int i = 0; i < 4; i++) {
        int nd = node0 + kg * 4 + i;
        g16[(size_t)nd * HDIM + cc] = (__half)(dis[nd] * acc[i]);
    }
}

#define ACC4(V) \
    a0 = __hadd2(a0, __builtin_bit_cast(__half2, (V).x)); \
    a1 = __hadd2(a1, __builtin_bit_cast(__half2, (V).y)); \
    a2 = __hadd2(a2, __builtin_bit_cast(__half2, (V).z)); \
    a3 = __hadd2(a3, __builtin_bit_cast(__half2, (V).w));

#define GATHER_LOOP \
    int e = e0 + 4 * half; \
    for (; e + 8 < e1; e += 16) { \
        int4 sa = *reinterpret_cast<const int4*>(srcidx + e); \
        int4 sb = *reinterpret_cast<const int4*>(srcidx + e + 8); \
        uint4 w0 = gp[(size_t)sa.x * 2 + piece]; \
        uint4 w1 = gp[(size_t)sa.y * 2 + piece]; \
        uint4 w2 = gp[(size_t)sa.z * 2 + piece]; \
        uint4 w3 = gp[(size_t)sa.w * 2 + piece]; \
        uint4 w4 = gp[(size_t)sb.x * 2 + piece]; \
        uint4 w5 = gp[(size_t)sb.y * 2 + piece]; \
        uint4 w6 = gp[(size_t)sb.z * 2 + piece]; \
        uint4 w7 = gp[(size_t)sb.w * 2 + piece]; \
        ACC4(w0) ACC4(w1) ACC4(w2) ACC4(w3) \
        ACC4(w4) ACC4(w5) ACC4(w6) ACC4(w7) \
    } \
    for (; e < e1; e += 8) { \
        int4 sa = *reinterpret_cast<const int4*>(srcidx + e); \
        uint4 w0 = gp[(size_t)sa.x * 2 + piece]; \
        uint4 w1 = gp[(size_t)sa.y * 2 + piece]; \
        uint4 w2 = gp[(size_t)sa.z * 2 + piece]; \
        uint4 w3 = gp[(size_t)sa.w * 2 + piece]; \
        ACC4(w0) ACC4(w1) ACC4(w2) ACC4(w3) \
    } \
    a0 = __hadd2(a0, __builtin_bit_cast(__half2, __shfl_xor(__builtin_bit_cast(unsigned, a0), 2))); \
    a1 = __hadd2(a1, __builtin_bit_cast(__half2, __shfl_xor(__builtin_bit_cast(unsigned, a1), 2))); \
    a2 = __hadd2(a2, __builtin_bit_cast(__half2, __shfl_xor(__builtin_bit_cast(unsigned, a2), 2))); \
    a3 = __hadd2(a3, __builtin_bit_cast(__half2, __shfl_xor(__builtin_bit_cast(unsigned, a3), 2)));

// layer-1 aggregation + fused W2 matmul (quadrant split across 4 sub-lanes).
__global__ __launch_bounds__(256) void k_agg_g2(const __half* __restrict__ g16in,
                                                const int2* __restrict__ off2,
                                                const int* __restrict__ srcidx,
                                                const float* __restrict__ dis,
                                                const float* __restrict__ bias,
                                                const float* __restrict__ W2,
                                                __half* __restrict__ g16out, int n) {
    __shared__ float W2s[HDIM * HDIM];
    int t = threadIdx.x;
    W2s[t] = W2[t];     // blockDim == 256 == HDIM*HDIM
    __syncthreads();
    int tid = blockIdx.x * 256 + t;
    int node = tid >> 2, sub = t & 3;
    int piece = sub & 1, half = sub >> 1;
    if (node >= n) return;
    const uint4* gp = reinterpret_cast<const uint4*>(g16in);
    int2 oe = off2[node];
    int e0 = oe.x, e1 = oe.y;
    __half2 a0{0, 0}, a1{0, 0}, a2{0, 0}, a3{0, 0};
    if (half == 0) {  // self-loop term once
        uint4 v = gp[(size_t)node * 2 + piece];
        ACC4(v)
    }
    GATHER_LOOP
    // all lanes: relu'd h for channels piece*8 .. piece*8+7
    float dn = dis[node];
    const float* bp = bias + piece * 8;
    float2 f0 = __half22float2(a0), f1 = __half22float2(a1);
    float2 f2 = __half22float2(a2), f3 = __half22float2(a3);
    float hreg[8];
    hreg[0] = fmaxf(dn * f0.x + bp[0], 0.f); hreg[1] = fmaxf(dn * f0.y + bp[1], 0.f);
    hreg[2] = fmaxf(dn * f1.x + bp[2], 0.f); hreg[3] = fmaxf(dn * f1.y + bp[3], 0.f);
    hreg[4] = fmaxf(dn * f2.x + bp[4], 0.f); hreg[5] = fmaxf(dn * f2.y + bp[5], 0.f);
    hreg[6] = fmaxf(dn * f3.x + bp[6], 0.f); hreg[7] = fmaxf(dn * f3.y + bp[7], 0.f);
    // quadrant of h @ W2: j-range = piece*8.., c-range = half*8..
    float acc[8];
    const float* wq = W2s + (piece * 8) * HDIM + half * 8;
#pragma unroll
    for (int cc = 0; cc < 8; cc++) {
        float s = 0.f;
#pragma unroll
        for (int jj = 0; jj < 8; jj++) s += hreg[jj] * wq[jj * HDIM + cc];
        acc[cc] = s;
    }
    // combine j-halves across piece (bit 0)
#pragma unroll
    for (int cc = 0; cc < 8; cc++) acc[cc] += __shfl_xor(acc[cc], 1);
    if (piece == 0) {   // sub0 writes c 0-7, sub2 writes c 8-15
        __half o[8];
#pragma unroll
        for (int cc = 0; cc < 8; cc++) o[cc] = (__half)(dn * acc[cc]);
        *reinterpret_cast<uint4*>(g16out + (size_t)node * HDIM + half * 8) =
            *reinterpret_cast<uint4*>(o);
    }
}

// layer-2 aggregation + fused global max pool (h never written).
__global__ __launch_bounds__(256) void k_agg_pool(const __half* __restrict__ g16in,
                                                  const int2* __restrict__ off2,
                                                  const int* __restrict__ srcidx,
                                                  const float* __restrict__ dis,
                                                  const float* __restrict__ bias,
                                                  unsigned int* __restrict__ pooled,
                                                  int n) {
    __shared__ float smax[4][16];
    int t = threadIdx.x;
    int tid = blockIdx.x * 256 + t;
    int node = tid >> 2, sub = t & 3;
    int piece = sub & 1, half = sub >> 1;
    bool active = node < n;
    float4 o0 = {0.f, 0.f, 0.f, 0.f}, o1 = {0.f, 0.f, 0.f, 0.f};
    if (active) {
        const uint4* gp = reinterpret_cast<const uint4*>(g16in);
        int2 oe = off2[node];
        int e0 = oe.x, e1 = oe.y;
        __half2 a0{0, 0}, a1{0, 0}, a2{0, 0}, a3{0, 0};
        if (half == 0) {  // self-loop term once
            uint4 v = gp[(size_t)node * 2 + piece];
            ACC4(v)
        }
        GATHER_LOOP
        if (half == 0) {
            float dn = dis[node];
            const float* bp = bias + piece * 8;
            float2 f0 = __half22float2(a0), f1 = __half22float2(a1);
            float2 f2 = __half22float2(a2), f3 = __half22float2(a3);
            o0.x = fmaxf(dn * f0.x + bp[0], 0.f); o0.y = fmaxf(dn * f0.y + bp[1], 0.f);
            o0.z = fmaxf(dn * f1.x + bp[2], 0.f); o0.w = fmaxf(dn * f1.y + bp[3], 0.f);
            o1.x = fmaxf(dn * f2.x + bp[4], 0.f); o1.y = fmaxf(dn * f2.y + bp[5], 0.f);
            o1.z = fmaxf(dn * f3.x + bp[6], 0.f); o1.w = fmaxf(dn * f3.y + bp[7], 0.f);
        }
    }
    // wave-reduce over nodes (xor >= 4 preserves sub class); h >= 0
#pragma unroll
    for (int d = 4; d <= 32; d <<= 1) {
        o0.x = fmaxf(o0.x, __shfl_xor(o0.x, d)); o0.y = fmaxf(o0.y, __shfl_xor(o0.y, d));
        o0.z = fmaxf(o0.z, __shfl_xor(o0.z, d)); o0.w = fmaxf(o0.w, __shfl_xor(o0.w, d));
        o1.x = fmaxf(o1.x, __shfl_xor(o1.x, d)); o1.y = fmaxf(o1.y, __shfl_xor(o1.y, d));
        o1.z = fmaxf(o1.z, __shfl_xor(o1.z, d)); o1.w = fmaxf(o1.w, __shfl_xor(o1.w, d));
    }
    int wv = t >> 6;
    if ((t & 63) < 2) {  // lane 0: piece0, lane 1: piece1 (half==0 class)
        float* sp = &smax[wv][piece * 8];
        sp[0] = o0.x; sp[1] = o0.y; sp[2] = o0.z; sp[3] = o0.w;
        sp[4] = o1.x; sp[5] = o1.y; sp[6] = o1.z; sp[7] = o1.w;
    }
    __syncthreads();
    if (t < 16) {
        float m = fmaxf(fmaxf(smax[0][t], smax[1][t]), fmaxf(smax[2][t], smax[3][t]));
        atomicMax(&pooled[t], __float_as_uint(m));
    }
}

// out[a] = sum_c pooled[c] * Wc[c][a] + bc[a]   (Wc: [16,10])
__global__ void k_final(const unsigned int* __restrict__ pooled, const float* __restrict__ Wc,
                        const float* __restrict__ bc, float* __restrict__ out) {
    __shared__ float p[HDIM];
    int t = threadIdx.x;
    if (t < HDIM) p[t] = __uint_as_float(pooled[t]);
    __syncthreads();
    if (t < AOUT) {
        float acc = bc[t];
#pragma unroll
        for (int c = 0; c < HDIM; c++) acc += p[c] * Wc[c * AOUT + t];
        out[t] = acc;
    }
}

extern "C" void kernel_launch(void* const* d_in, const int* in_sizes, int n_in,
                              void* d_out, int out_size, void* d_ws, size_t ws_size,
                              hipStream_t stream) {
    const float* x  = (const float*)d_in[0];
    const int*   ei = (const int*)d_in[1];
    const float* W1 = (const float*)d_in[2];
    const float* b1 = (const float*)d_in[3];
    const float* W2 = (const float*)d_in[4];
    const float* b2 = (const float*)d_in[5];
    const float* Wc = (const float*)d_in[6];
    const float* bc = (const float*)d_in[7];
    float* out = (float*)d_out;

    int n = in_sizes[0] / FIN;
    int E = in_sizes[1] / 2;
    const int* srcp = ei;       // edge_index[0]
    const int* dstp = ei + E;   // edge_index[1]
    int K = (n + NPB - 1) / NPB;   // 391 for n=100000

    char* ws = (char*)d_ws;
    auto alloc = [&](size_t bytes) -> char* {
        char* p = ws;
        ws += (bytes + 255) & ~(size_t)255;
        return p;
    };
    float*        dis   = (float*)alloc((size_t)n * 4);
    int*          bcur  = (int*)alloc((size_t)K * 4);
    int2*         off2  = (int2*)alloc((size_t)n * 8);
    unsigned int* pairs = (unsigned int*)alloc((size_t)K * CAP * 4);
    int*          srcidx= (int*)alloc((size_t)K * CAP * 4);
    __half*       g16a  = (__half*)alloc((size_t)(n + 1) * HDIM * 2);
    __half*       g16b  = (__half*)alloc((size_t)(n + 1) * HDIM * 2);
    unsigned int* pooled= (unsigned int*)alloc(64);

    k_init<<<(K + 255) / 256, 256, 0, stream>>>(
        bcur, pooled,
        (unsigned int*)(g16a + (size_t)n * HDIM),
        (unsigned int*)(g16b + (size_t)n * HDIM), K);
    k_bin<<<(E + TILE - 1) / TILE, 512, 0, stream>>>(srcp, dstp, E, bcur, pairs, K);
    k_sort<<<K, 1024, 0, stream>>>(pairs, bcur, srcidx, off2, dis, n);

    int ntile = (n + 15) / 16;
    int gblocks = (ntile + 3) / 4;
    k_gemm1<<<gblocks, 256, 0, stream>>>(x, W1, dis, g16a, n);
    k_agg_g2<<<(4 * n + 255) / 256, 256, 0, stream>>>(g16a, off2, srcidx, dis, b1,
                                                      W2, g16b, n);
    k_agg_pool<<<(4 * n + 255) / 256, 256, 0, stream>>>(g16b, off2, srcidx, dis, b2,
                                                        pooled, n);

    k_final<<<1, 64, 0, stream>>>(pooled, Wc, bc, out);
}

// Round 18
// 122.919 us; speedup vs baseline: 1.0935x; 1.0049x over previous
//
#include <hip/hip_runtime.h>
#include <hip/hip_fp16.h>

// GCN policy net: 2× GCNConv(H=16) + global max pool + linear head.
// Build: fixed-capacity coarse buckets -> k_bin (TILE=4096 x 512 thr,
// wave-shfl scan; phase-3 batches all 8 independent LDS atomicAdds before
// the dependent buf writes — k_bin is chain-throughput-bound per round 15)
// -> k_sort (1024 thr, uint4-vectorized single pairs read, wave-shfl scan;
// 4-aligned segments, sentinel pad -> zero g16 row; off2 + dis).
// Compute: MFMA f16 gemm1; layer-1 agg fuses the 16x16 W2 matmul in its
// epilogue -> g16b; layer-2 agg fuses global max pool. Separate k_final
// (round-12 lesson: per-block __threadfence = full-L2 writeback x blocks).

#define FIN 128
#define HDIM 16
#define AOUT 10
#define NPB 256      // nodes per bucket (bucket = dst >> 8)
#define KMAX 512     // LDS sizing bound (padded): supports n <= 131072
#define TILE 4096    // edges per k_bin tile (2048 proven worse, round 15)
#define CAP 10240    // bucket capacity (max count ~8560 + align pad <=768)

typedef _Float16 f16x8 __attribute__((ext_vector_type(8)));
typedef float f32x4 __attribute__((ext_vector_type(4)));

// init bucket cursors; zero pooled; zero sentinel rows of g16 buffers
__global__ void k_init(int* __restrict__ bcur, unsigned int* __restrict__ pooled,
                       unsigned int* __restrict__ gza, unsigned int* __restrict__ gzb,
                       int K) {
    int i = blockIdx.x * 256 + threadIdx.x;
    if (i < K) bcur[i] = i * CAP;
    if (i < 16) pooled[i] = 0u;
    if (i < 8) { gza[i] = 0u; gzb[i] = 0u; }   // 32B zero rows
}

// tile-local reorder: histogram -> wave-shfl scan (2 barriers) ->
// bucket-sorted LDS buffer (batched atomics) -> linear coalesced copy-out.
__global__ __launch_bounds__(512) void k_bin(const int* __restrict__ src,
                                             const int* __restrict__ dst, int E,
                                             int* __restrict__ bcur,
                                             unsigned int* __restrict__ pairs, int K) {
    __shared__ int hist[KMAX], lofs[KMAX], run[KMAX], gbase[KMAX];
    __shared__ int wsum[8];
    __shared__ unsigned int buf[TILE];
    __shared__ unsigned short bkt[TILE];
    int t = threadIdx.x;
    int lane = t & 63, wv = t >> 6;
    int e0 = blockIdx.x * TILE;
    int e1 = min(E, e0 + TILE);
    hist[t] = 0;                       // blockDim == KMAX == 512
    __syncthreads();
    int eA = e0 + t * 4;
    int eB = eA + 2048;
    bool fA = (eA + 4 <= e1), fB = (eB + 4 <= e1);
    // phase 1: tile histogram (both iterations' loads hoisted)
    {
        int4 dA, dB;
        if (fA) dA = *reinterpret_cast<const int4*>(dst + eA);
        if (fB) dB = *reinterpret_cast<const int4*>(dst + eB);
        if (fA) {
            atomicAdd(&hist[dA.x >> 8], 1);
            atomicAdd(&hist[dA.y >> 8], 1);
            atomicAdd(&hist[dA.z >> 8], 1);
            atomicAdd(&hist[dA.w >> 8], 1);
        } else if (eA < e1) {
            for (int q = eA; q < e1; q++) atomicAdd(&hist[dst[q] >> 8], 1);
        }
        if (fB) {
            atomicAdd(&hist[dB.x >> 8], 1);
            atomicAdd(&hist[dB.y >> 8], 1);
            atomicAdd(&hist[dB.z >> 8], 1);
            atomicAdd(&hist[dB.w >> 8], 1);
        } else if (eB < e1) {
            for (int q = eB; q < e1; q++) atomicAdd(&hist[dst[q] >> 8], 1);
        }
    }
    __syncthreads();
    // phase 2: exclusive scan via wave shfl (2 barriers total)
    int a = hist[t];
    int v = a;
#pragma unroll
    for (int d = 1; d < 64; d <<= 1) {
        int u = __shfl_up(v, d);
        if (lane >= d) v += u;
    }
    if (lane == 63) wsum[wv] = v;
    __syncthreads();
    int woff = 0;
#pragma unroll
    for (int w2 = 0; w2 < 8; w2++) woff += (w2 < wv) ? wsum[w2] : 0;
    int excl = v + woff - a;           // exclusive prefix
    lofs[t] = excl;
    run[t] = excl;
    // reserve global windows (one atomic per non-empty bucket)
    if (t < K && a) gbase[t] = atomicAdd(&bcur[t], a);
    __syncthreads();
    // phase 3: scatter into bucket-sorted LDS buffer.
    // All 8 independent LDS atomicAdds issued before the dependent writes.
    {
        int4 dA, sA, dB, sB;
        if (fA) {
            dA = *reinterpret_cast<const int4*>(dst + eA);
            sA = *reinterpret_cast<const int4*>(src + eA);
        }
        if (fB) {
            dB = *reinterpret_cast<const int4*>(dst + eB);
            sB = *reinterpret_cast<const int4*>(src + eB);
        }
        int rA0, rA1, rA2, rA3, rB0, rB1, rB2, rB3;
        if (fA) {
            rA0 = atomicAdd(&run[dA.x >> 8], 1);
            rA1 = atomicAdd(&run[dA.y >> 8], 1);
            rA2 = atomicAdd(&run[dA.z >> 8], 1);
            rA3 = atomicAdd(&run[dA.w >> 8], 1);
        }
        if (fB) {
            rB0 = atomicAdd(&run[dB.x >> 8], 1);
            rB1 = atomicAdd(&run[dB.y >> 8], 1);
            rB2 = atomicAdd(&run[dB.z >> 8], 1);
            rB3 = atomicAdd(&run[dB.w >> 8], 1);
        }
        if (fA) {
            buf[rA0] = (unsigned)sA.x | ((unsigned)(dA.x & 255) << 17); bkt[rA0] = (unsigned short)(dA.x >> 8);
            buf[rA1] = (unsigned)sA.y | ((unsigned)(dA.y & 255) << 17); bkt[rA1] = (unsigned short)(dA.y >> 8);
            buf[rA2] = (unsigned)sA.z | ((unsigned)(dA.z & 255) << 17); bkt[rA2] = (unsigned short)(dA.z >> 8);
            buf[rA3] = (unsigned)sA.w | ((unsigned)(dA.w & 255) << 17); bkt[rA3] = (unsigned short)(dA.w >> 8);
        } else if (eA < e1) {
            for (int q = eA; q < e1; q++) {
                int d = dst[q], s = src[q], b = d >> 8;
                int r = atomicAdd(&run[b], 1);
                buf[r] = (unsigned)s | ((unsigned)(d & 255) << 17);
                bkt[r] = (unsigned short)b;
            }
        }
        if (fB) {
            buf[rB0] = (unsigned)sB.x | ((unsigned)(dB.x & 255) << 17); bkt[rB0] = (unsigned short)(dB.x >> 8);
            buf[rB1] = (unsigned)sB.y | ((unsigned)(dB.y & 255) << 17); bkt[rB1] = (unsigned short)(dB.y >> 8);
            buf[rB2] = (unsigned)sB.z | ((unsigned)(dB.z & 255) << 17); bkt[rB2] = (unsigned short)(dB.z >> 8);
            buf[rB3] = (unsigned)sB.w | ((unsigned)(dB.w & 255) << 17); bkt[rB3] = (unsigned short)(dB.w >> 8);
        } else if (eB < e1) {
            for (int q = eB; q < e1; q++) {
                int d = dst[q], s = src[q], b = d >> 8;
                int r = atomicAdd(&run[b], 1);
                buf[r] = (unsigned)s | ((unsigned)(d & 255) << 17);
                bkt[r] = (unsigned short)b;
            }
        }
    }
    __syncthreads();
    // phase 4: linear coalesced copy-out
    int m = e1 - e0;
    for (int i = t; i < m; i += 512) {
        int b = bkt[i];
        pairs[gbase[b] + i - lofs[b]] = buf[i];
    }
}

// per-bucket counting sort (1024 thr, uint4-vectorized single pairs read,
// wave-shfl scan) -> node-ordered srcidx with 4-aligned segments + off2 + dis.
__global__ __launch_bounds__(1024) void k_sort(const unsigned int* __restrict__ pairs,
                                               const int* __restrict__ bcur,
                                               int* __restrict__ srcidx,
                                               int2* __restrict__ off2,
                                               float* __restrict__ dis, int n) {
    __shared__ int lcnt[NPB], cur[NPB];
    __shared__ int wsum4[4];
    int b = blockIdx.x, t = threadIdx.x;
    int lane = t & 63, wv = t >> 6;
    if (t < NPB) lcnt[t] = 0;
    __syncthreads();
    int base = b * CAP;
    int m = bcur[b] - base;
    int m4 = (m + 3) >> 2;             // uint4 count
    const uint4* p4 = reinterpret_cast<const uint4*>(pairs + base);
    uint4 l0 = {0,0,0,0}, l1 = {0,0,0,0}, l2 = {0,0,0,0};
    if (t < m4) {
        l0 = p4[t];
        int jj = t * 4;
        atomicAdd(&lcnt[l0.x >> 17], 1);
        if (jj + 1 < m) atomicAdd(&lcnt[l0.y >> 17], 1);
        if (jj + 2 < m) atomicAdd(&lcnt[l0.z >> 17], 1);
        if (jj + 3 < m) atomicAdd(&lcnt[l0.w >> 17], 1);
    }
    if (t + 1024 < m4) {
        l1 = p4[t + 1024];
        int jj = (t + 1024) * 4;
        atomicAdd(&lcnt[l1.x >> 17], 1);
        if (jj + 1 < m) atomicAdd(&lcnt[l1.y >> 17], 1);
        if (jj + 2 < m) atomicAdd(&lcnt[l1.z >> 17], 1);
        if (jj + 3 < m) atomicAdd(&lcnt[l1.w >> 17], 1);
    }
    if (t + 2048 < m4) {
        l2 = p4[t + 2048];
        int jj = (t + 2048) * 4;
        atomicAdd(&lcnt[l2.x >> 17], 1);
        if (jj + 1 < m) atomicAdd(&lcnt[l2.y >> 17], 1);
        if (jj + 2 < m) atomicAdd(&lcnt[l2.z >> 17], 1);
        if (jj + 3 < m) atomicAdd(&lcnt[l2.w >> 17], 1);
    }
    __syncthreads();
    // wave-shfl exclusive scan over aligned sizes (threads 0..255 = 4 waves)
    int v = (t < NPB) ? lcnt[t] : 0;
    int w = (v + 3) & ~3;              // 4-aligned segment size
    int s = w;
    if (t < NPB) {
#pragma unroll
        for (int d = 1; d < 64; d <<= 1) {
            int u = __shfl_up(s, d);
            if (lane >= d) s += u;
        }
        if (lane == 63) wsum4[wv] = s;
    }
    __syncthreads();
    if (t < NPB) {
        int woff = 0;
#pragma unroll
        for (int w2 = 0; w2 < 4; w2++) woff += (w2 < wv) ? wsum4[w2] : 0;
        int start = s + woff - w;      // exclusive prefix
        cur[t] = start;
        int node = (b << 8) + t;
        if (node < n) {
            off2[node] = make_int2(base + start, base + start + v);
            dis[node] = rsqrtf((float)(v + 1));
        }
        for (int p = v; p < w; p++) srcidx[base + start + p] = n;  // sentinel
    }
    __syncthreads();
    // scatter from registers
    if (t < m4) {
        int jj = t * 4;
        unsigned p;
        p = l0.x; srcidx[base + atomicAdd(&cur[p >> 17], 1)] = (int)(p & 0x1FFFF);
        if (jj + 1 < m) { p = l0.y; srcidx[base + atomicAdd(&cur[p >> 17], 1)] = (int)(p & 0x1FFFF); }
        if (jj + 2 < m) { p = l0.z; srcidx[base + atomicAdd(&cur[p >> 17], 1)] = (int)(p & 0x1FFFF); }
        if (jj + 3 < m) { p = l0.w; srcidx[base + atomicAdd(&cur[p >> 17], 1)] = (int)(p & 0x1FFFF); }
    }
    if (t + 1024 < m4) {
        int jj = (t + 1024) * 4;
        unsigned p;
        p = l1.x; srcidx[base + atomicAdd(&cur[p >> 17], 1)] = (int)(p & 0x1FFFF);
        if (jj + 1 < m) { p = l1.y; srcidx[base + atomicAdd(&cur[p >> 17], 1)] = (int)(p & 0x1FFFF); }
        if (jj + 2 < m) { p = l1.z; srcidx[base + atomicAdd(&cur[p >> 17], 1)] = (int)(p & 0x1FFFF); }
        if (jj + 3 < m) { p = l1.w; srcidx[base + atomicAdd(&cur[p >> 17], 1)] = (int)(p & 0x1FFFF); }
    }
    if (t + 2048 < m4) {
        int jj = (t + 2048) * 4;
        unsigned p;
        p = l2.x; srcidx[base + atomicAdd(&cur[p >> 17], 1)] = (int)(p & 0x1FFFF);
        if (jj + 1 < m) { p = l2.y; srcidx[base + atomicAdd(&cur[p >> 17], 1)] = (int)(p & 0x1FFFF); }
        if (jj + 2 < m) { p = l2.z; srcidx[base + atomicAdd(&cur[p >> 17], 1)] = (int)(p & 0x1FFFF); }
        if (jj + 3 < m) { p = l2.w; srcidx[base + atomicAdd(&cur[p >> 17], 1)] = (int)(p & 0x1FFFF); }
    }
}

// MFMA gemm1: g16[nd][c] = f16(dis[nd] * (x @ W1)[nd][c]).
__global__ __launch_bounds__(256) void k_gemm1(const float* __restrict__ x,
                                               const float* __restrict__ W1,
                                               const float* __restrict__ dis,
                                               __half* __restrict__ g16, int n) {
    int l = threadIdx.x & 63;
    int cc = l & 15, kg = l >> 4;
    f16x8 bfrag[4];
#pragma unroll
    for (int kc = 0; kc < 4; kc++)
#pragma unroll
        for (int j = 0; j < 8; j++)
            bfrag[kc][j] = (_Float16)W1[(kc * 32 + kg * 8 + j) * HDIM + cc];
    int tile = blockIdx.x * 4 + (threadIdx.x >> 6);
    int node0 = tile * 16;
    if (node0 >= n) return;
    const float* xr = x + (size_t)(node0 + cc) * FIN;
    f32x4 acc = {0.f, 0.f, 0.f, 0.f};
#pragma unroll
    for (int kc = 0; kc < 4; kc++) {
        float4 xa = *reinterpret_cast<const float4*>(xr + kc * 32 + kg * 8);
        float4 xb = *reinterpret_cast<const float4*>(xr + kc * 32 + kg * 8 + 4);
        f16x8 a;
        a[0] = (_Float16)xa.x; a[1] = (_Float16)xa.y;
        a[2] = (_Float16)xa.z; a[3] = (_Float16)xa.w;
        a[4] = (_Float16)xb.x; a[5] = (_Float16)xb.y;
        a[6] = (_Float16)xb.z; a[7] = (_Float16)xb.w;
        acc = __builtin_amdgcn_mfma_f32_16x16x32_f16(a, bfrag[kc], acc, 0, 0, 0);
    }
#pragma unroll
    for (int i = 0; i < 4; i++) {
        int nd = node0 + kg * 4 + i;
        g16[(size_t)nd * HDIM + cc] = (__half)(dis[nd] * acc[i]);
    }
}

#define ACC4(V) \
    a0 = __hadd2(a0, __builtin_bit_cast(__half2, (V).x)); \
    a1 = __hadd2(a1, __builtin_bit_cast(__half2, (V).y)); \
    a2 = __hadd2(a2, __builtin_bit_cast(__half2, (V).z)); \
    a3 = __hadd2(a3, __builtin_bit_cast(__half2, (V).w));

#define GATHER_LOOP \
    int e = e0 + 4 * half; \
    for (; e + 8 < e1; e += 16) { \
        int4 sa = *reinterpret_cast<const int4*>(srcidx + e); \
        int4 sb = *reinterpret_cast<const int4*>(srcidx + e + 8); \
        uint4 w0 = gp[(size_t)sa.x * 2 + piece]; \
        uint4 w1 = gp[(size_t)sa.y * 2 + piece]; \
        uint4 w2 = gp[(size_t)sa.z * 2 + piece]; \
        uint4 w3 = gp[(size_t)sa.w * 2 + piece]; \
        uint4 w4 = gp[(size_t)sb.x * 2 + piece]; \
        uint4 w5 = gp[(size_t)sb.y * 2 + piece]; \
        uint4 w6 = gp[(size_t)sb.z * 2 + piece]; \
        uint4 w7 = gp[(size_t)sb.w * 2 + piece]; \
        ACC4(w0) ACC4(w1) ACC4(w2) ACC4(w3) \
        ACC4(w4) ACC4(w5) ACC4(w6) ACC4(w7) \
    } \
    for (; e < e1; e += 8) { \
        int4 sa = *reinterpret_cast<const int4*>(srcidx + e); \
        uint4 w0 = gp[(size_t)sa.x * 2 + piece]; \
        uint4 w1 = gp[(size_t)sa.y * 2 + piece]; \
        uint4 w2 = gp[(size_t)sa.z * 2 + piece]; \
        uint4 w3 = gp[(size_t)sa.w * 2 + piece]; \
        ACC4(w0) ACC4(w1) ACC4(w2) ACC4(w3) \
    } \
    a0 = __hadd2(a0, __builtin_bit_cast(__half2, __shfl_xor(__builtin_bit_cast(unsigned, a0), 2))); \
    a1 = __hadd2(a1, __builtin_bit_cast(__half2, __shfl_xor(__builtin_bit_cast(unsigned, a1), 2))); \
    a2 = __hadd2(a2, __builtin_bit_cast(__half2, __shfl_xor(__builtin_bit_cast(unsigned, a2), 2))); \
    a3 = __hadd2(a3, __builtin_bit_cast(__half2, __shfl_xor(__builtin_bit_cast(unsigned, a3), 2)));

// layer-1 aggregation + fused W2 matmul (quadrant split across 4 sub-lanes).
__global__ __launch_bounds__(256) void k_agg_g2(const __half* __restrict__ g16in,
                                                const int2* __restrict__ off2,
                                                const int* __restrict__ srcidx,
                                                const float* __restrict__ dis,
                                                const float* __restrict__ bias,
                                                const float* __restrict__ W2,
                                                __half* __restrict__ g16out, int n) {
    __shared__ float W2s[HDIM * HDIM];
    int t = threadIdx.x;
    W2s[t] = W2[t];     // blockDim == 256 == HDIM*HDIM
    __syncthreads();
    int tid = blockIdx.x * 256 + t;
    int node = tid >> 2, sub = t & 3;
    int piece = sub & 1, half = sub >> 1;
    if (node >= n) return;
    const uint4* gp = reinterpret_cast<const uint4*>(g16in);
    int2 oe = off2[node];
    int e0 = oe.x, e1 = oe.y;
    __half2 a0{0, 0}, a1{0, 0}, a2{0, 0}, a3{0, 0};
    if (half == 0) {  // self-loop term once
        uint4 v = gp[(size_t)node * 2 + piece];
        ACC4(v)
    }
    GATHER_LOOP
    // all lanes: relu'd h for channels piece*8 .. piece*8+7
    float dn = dis[node];
    const float* bp = bias + piece * 8;
    float2 f0 = __half22float2(a0), f1 = __half22float2(a1);
    float2 f2 = __half22float2(a2), f3 = __half22float2(a3);
    float hreg[8];
    hreg[0] = fmaxf(dn * f0.x + bp[0], 0.f); hreg[1] = fmaxf(dn * f0.y + bp[1], 0.f);
    hreg[2] = fmaxf(dn * f1.x + bp[2], 0.f); hreg[3] = fmaxf(dn * f1.y + bp[3], 0.f);
    hreg[4] = fmaxf(dn * f2.x + bp[4], 0.f); hreg[5] = fmaxf(dn * f2.y + bp[5], 0.f);
    hreg[6] = fmaxf(dn * f3.x + bp[6], 0.f); hreg[7] = fmaxf(dn * f3.y + bp[7], 0.f);
    // quadrant of h @ W2: j-range = piece*8.., c-range = half*8..
    float acc[8];
    const float* wq = W2s + (piece * 8) * HDIM + half * 8;
#pragma unroll
    for (int cc = 0; cc < 8; cc++) {
        float s = 0.f;
#pragma unroll
        for (int jj = 0; jj < 8; jj++) s += hreg[jj] * wq[jj * HDIM + cc];
        acc[cc] = s;
    }
    // combine j-halves across piece (bit 0)
#pragma unroll
    for (int cc = 0; cc < 8; cc++) acc[cc] += __shfl_xor(acc[cc], 1);
    if (piece == 0) {   // sub0 writes c 0-7, sub2 writes c 8-15
        __half o[8];
#pragma unroll
        for (int cc = 0; cc < 8; cc++) o[cc] = (__half)(dn * acc[cc]);
        *reinterpret_cast<uint4*>(g16out + (size_t)node * HDIM + half * 8) =
            *reinterpret_cast<uint4*>(o);
    }
}

// layer-2 aggregation + fused global max pool (h never written).
__global__ __launch_bounds__(256) void k_agg_pool(const __half* __restrict__ g16in,
                                                  const int2* __restrict__ off2,
                                                  const int* __restrict__ srcidx,
                                                  const float* __restrict__ dis,
                                                  const float* __restrict__ bias,
                                                  unsigned int* __restrict__ pooled,
                                                  int n) {
    __shared__ float smax[4][16];
    int t = threadIdx.x;
    int tid = blockIdx.x * 256 + t;
    int node = tid >> 2, sub = t & 3;
    int piece = sub & 1, half = sub >> 1;
    bool active = node < n;
    float4 o0 = {0.f, 0.f, 0.f, 0.f}, o1 = {0.f, 0.f, 0.f, 0.f};
    if (active) {
        const uint4* gp = reinterpret_cast<const uint4*>(g16in);
        int2 oe = off2[node];
        int e0 = oe.x, e1 = oe.y;
        __half2 a0{0, 0}, a1{0, 0}, a2{0, 0}, a3{0, 0};
        if (half == 0) {  // self-loop term once
            uint4 v = gp[(size_t)node * 2 + piece];
            ACC4(v)
        }
        GATHER_LOOP
        if (half == 0) {
            float dn = dis[node];
            const float* bp = bias + piece * 8;
            float2 f0 = __half22float2(a0), f1 = __half22float2(a1);
            float2 f2 = __half22float2(a2), f3 = __half22float2(a3);
            o0.x = fmaxf(dn * f0.x + bp[0], 0.f); o0.y = fmaxf(dn * f0.y + bp[1], 0.f);
            o0.z = fmaxf(dn * f1.x + bp[2], 0.f); o0.w = fmaxf(dn * f1.y + bp[3], 0.f);
            o1.x = fmaxf(dn * f2.x + bp[4], 0.f); o1.y = fmaxf(dn * f2.y + bp[5], 0.f);
            o1.z = fmaxf(dn * f3.x + bp[6], 0.f); o1.w = fmaxf(dn * f3.y + bp[7], 0.f);
        }
    }
    // wave-reduce over nodes (xor >= 4 preserves sub class); h >= 0
#pragma unroll
    for (int d = 4; d <= 32; d <<= 1) {
        o0.x = fmaxf(o0.x, __shfl_xor(o0.x, d)); o0.y = fmaxf(o0.y, __shfl_xor(o0.y, d));
        o0.z = fmaxf(o0.z, __shfl_xor(o0.z, d)); o0.w = fmaxf(o0.w, __shfl_xor(o0.w, d));
        o1.x = fmaxf(o1.x, __shfl_xor(o1.x, d)); o1.y = fmaxf(o1.y, __shfl_xor(o1.y, d));
        o1.z = fmaxf(o1.z, __shfl_xor(o1.z, d)); o1.w = fmaxf(o1.w, __shfl_xor(o1.w, d));
    }
    int wv = t >> 6;
    if ((t & 63) < 2) {  // lane 0: piece0, lane 1: piece1 (half==0 class)
        float* sp = &smax[wv][piece * 8];
        sp[0] = o0.x; sp[1] = o0.y; sp[2] = o0.z; sp[3] = o0.w;
        sp[4] = o1.x; sp[5] = o1.y; sp[6] = o1.z; sp[7] = o1.w;
    }
    __syncthreads();
    if (t < 16) {
        float m = fmaxf(fmaxf(smax[0][t], smax[1][t]), fmaxf(smax[2][t], smax[3][t]));
        atomicMax(&pooled[t], __float_as_uint(m));
    }
}

// out[a] = sum_c pooled[c] * Wc[c][a] + bc[a]   (Wc: [16,10])
__global__ void k_final(const unsigned int* __restrict__ pooled, const float* __restrict__ Wc,
                        const float* __restrict__ bc, float* __restrict__ out) {
    __shared__ float p[HDIM];
    int t = threadIdx.x;
    if (t < HDIM) p[t] = __uint_as_float(pooled[t]);
    __syncthreads();
    if (t < AOUT) {
        float acc = bc[t];
#pragma unroll
        for (int c = 0; c < HDIM; c++) acc += p[c] * Wc[c * AOUT + t];
        out[t] = acc;
    }
}

extern "C" void kernel_launch(void* const* d_in, const int* in_sizes, int n_in,
                              void* d_out, int out_size, void* d_ws, size_t ws_size,
                              hipStream_t stream) {
    const float* x  = (const float*)d_in[0];
    const int*   ei = (const int*)d_in[1];
    const float* W1 = (const float*)d_in[2];
    const float* b1 = (const float*)d_in[3];
    const float* W2 = (const float*)d_in[4];
    const float* b2 = (const float*)d_in[5];
    const float* Wc = (const float*)d_in[6];
    const float* bc = (const float*)d_in[7];
    float* out = (float*)d_out;

    int n = in_sizes[0] / FIN;
    int E = in_sizes[1] / 2;
    const int* srcp = ei;       // edge_index[0]
    const int* dstp = ei + E;   // edge_index[1]
    int K = (n + NPB - 1) / NPB;   // 391 for n=100000

    char* ws = (char*)d_ws;
    auto alloc = [&](size_t bytes) -> char* {
        char* p = ws;
        ws += (bytes + 255) & ~(size_t)255;
        return p;
    };
    float*        dis   = (float*)alloc((size_t)n * 4);
    int*          bcur  = (int*)alloc((size_t)K * 4);
    int2*         off2  = (int2*)alloc((size_t)n * 8);
    unsigned int* pairs = (unsigned int*)alloc((size_t)K * CAP * 4);
    int*          srcidx= (int*)alloc((size_t)K * CAP * 4);
    __half*       g16a  = (__half*)alloc((size_t)(n + 1) * HDIM * 2);
    __half*       g16b  = (__half*)alloc((size_t)(n + 1) * HDIM * 2);
    unsigned int* pooled= (unsigned int*)alloc(64);

    k_init<<<(K + 255) / 256, 256, 0, stream>>>(
        bcur, pooled,
        (unsigned int*)(g16a + (size_t)n * HDIM),
        (unsigned int*)(g16b + (size_t)n * HDIM), K);
    k_bin<<<(E + TILE - 1) / TILE, 512, 0, stream>>>(srcp, dstp, E, bcur, pairs, K);
    k_sort<<<K, 1024, 0, stream>>>(pairs, bcur, srcidx, off2, dis, n);

    int ntile = (n + 15) / 16;
    int gblocks = (ntile + 3) / 4;
    k_gemm1<<<gblocks, 256, 0, stream>>>(x, W1, dis, g16a, n);
    k_agg_g2<<<(4 * n + 255) / 256, 256, 0, stream>>>(g16a, off2, srcidx, dis, b1,
                                                      W2, g16b, n);
    k_agg_pool<<<(4 * n + 255) / 256, 256, 0, stream>>>(g16b, off2, srcidx, dis, b2,
                                                        pooled, n);

    k_final<<<1, 64, 0, stream>>>(pooled, Wc, bc, out);
}